// Round 1
// 341.403 us; speedup vs baseline: 1.1350x; 1.1350x over previous
//
#include <hip/hip_runtime.h>

#define IN_DIM 1024
#define N_NEURONS 1024
#define N_SOMA 16384
#define BT 64          // batch tile
#define NB 4096        // batch size

typedef _Float16 h8 __attribute__((ext_vector_type(8)));

__device__ __forceinline__ float leaky(float v) { return v >= 0.0f ? v : 0.1f * v; }

// acc += (selected f16 half of u) * w, full f32 fma — no separate v_cvt.
#define MIX2(alo, ahi, u, w)                                          \
  asm("v_fma_mix_f32 %0, %2, %3, %0 op_sel_hi:[1,0,0]\n\t"            \
      "v_fma_mix_f32 %1, %2, %3, %1 op_sel:[1,0,0] op_sel_hi:[1,0,0]" \
      : "+v"(alo), "+v"(ahi)                                          \
      : "v"(u), "v"(w))

// ---- K0 fused prep: blocks [0,4096) compact pairs, [4096,4352) transpose x ----
__global__ __launch_bounds__(256) void prep_kernel(
    const float* __restrict__ x, _Float16* __restrict__ xt,
    const float* __restrict__ Wd, const float* __restrict__ mask,
    uint2* __restrict__ pairs) {
  if (blockIdx.x < 4096) {
    // compact: one wave per soma row. Offset stored with XOR-swizzle baked in:
    // off = (f<<7) | ((f&7)<<4)  -> reader XORs with (j<<4).
    const int lane = threadIdx.x & 63;
    const int s = (blockIdx.x << 2) + (threadIdx.x >> 6);
    const float* mrow = mask + (size_t)s * IN_DIM + lane * 16;
    const float* wrow = Wd + (size_t)s * IN_DIM + lane * 16;
    float m[16], w[16];
#pragma unroll
    for (int k = 0; k < 4; ++k) {
      *(float4*)(m + 4 * k) = *(const float4*)(mrow + 4 * k);
      *(float4*)(w + 4 * k) = *(const float4*)(wrow + 4 * k);
    }
    int c = 0;
#pragma unroll
    for (int k = 0; k < 16; ++k) c += (m[k] != 0.0f) ? 1 : 0;
    int inc = c;
#pragma unroll
    for (int d = 1; d < 64; d <<= 1) {
      int t = __shfl_up(inc, d);
      if (lane >= d) inc += t;
    }
    int pos = inc - c;
    uint2* prow = pairs + ((size_t)s << 5);
#pragma unroll
    for (int k = 0; k < 16; ++k) {
      if (m[k] != 0.0f) {
        if (pos < 32) {
          const unsigned f = (unsigned)(lane * 16 + k);
          prow[pos] = make_uint2(__float_as_uint(w[k] * m[k]),
                                 (f << 7) | ((f & 7) << 4));
        }
        ++pos;
      }
    }
  } else {
    // transpose x [B][F] f32 -> xt tiled [bt][f][64] f16 (coalesced reads)
    const int id = blockIdx.x - 4096;  // 0..255
    const int f = (id & 3) * 256 + threadIdx.x;
    const int bt = id >> 2;
    const int b0 = bt * BT;
    h8* dst = (h8*)xt + ((size_t)bt * IN_DIM + f) * 8;
#pragma unroll
    for (int o = 0; o < 8; ++o) {
      h8 v;
#pragma unroll
      for (int e = 0; e < 8; ++e)
        v[e] = (_Float16)x[(size_t)(b0 + o * 8 + e) * IN_DIM + f];
      dst[o] = v;
    }
  }
}

// ---- K1: fused sparse-dendrite + block-diagonal soma layer ----
// grid (8, 64): x = neuron tile (128), y = batch tile (64). block 1024 = 16 waves.
// wave = 8 neurons (n=lane>>3) x 8 batch-octs (j=lane&7); lane owns 1 neuron x 8 batches.
__global__ __launch_bounds__(1024) void dendrite_kernel(
    const _Float16* __restrict__ xt, const uint2* __restrict__ pairs,
    const float* __restrict__ bd, const float* __restrict__ Ws,
    const float* __restrict__ bs, float* __restrict__ out) {
  __shared__ _Float16 xs[IN_DIM * BT];  // 128 KB; row f = 128 B
  // stage with XOR swizzle: 16B chunk (f,j) -> slot (f, j^(f&7)).
  // Breaks the "every row starts at bank 0" 8-way ds_read conflict.
  const uint4* src = (const uint4*)(xt + (size_t)blockIdx.y * IN_DIM * BT);
  uint4* dst = (uint4*)xs;
  for (int q = threadIdx.x; q < IN_DIM * BT * 2 / 16; q += 1024)
    dst[q ^ ((q >> 3) & 7)] = src[q];
  __syncthreads();

  const int lane = threadIdx.x & 63;
  const int wv = threadIdx.x >> 6;  // 0..15
  const int n = lane >> 3;          // neuron within wave
  const int j = lane & 7;           // batch oct
  const unsigned jx = (unsigned)j << 4;
  const int i = blockIdx.x * 128 + wv * 8 + n;  // neuron id
  const char* xsb = (const char*)xs;

  float p[8] = {0.f, 0.f, 0.f, 0.f, 0.f, 0.f, 0.f, 0.f};
  const float* wsrow = Ws + (size_t)i * N_SOMA + (i << 4);
  const float* bdrow = bd + (i << 4);

  for (int g = 0; g < 16; ++g) {
    const uint4* pr = (const uint4*)(pairs + (((size_t)(i << 4) + g) << 5));
    float a[8] = {0.f, 0.f, 0.f, 0.f, 0.f, 0.f, 0.f, 0.f};
#pragma unroll
    for (int k = 0; k < 16; ++k) {
      const uint4 p4 = pr[k];
      const uint4 u1 = *(const uint4*)(xsb + (p4.y ^ jx));
      const uint4 u2 = *(const uint4*)(xsb + (p4.w ^ jx));
      const float w1 = __uint_as_float(p4.x);
      const float w2 = __uint_as_float(p4.z);
      MIX2(a[0], a[1], u1.x, w1);
      MIX2(a[2], a[3], u1.y, w1);
      MIX2(a[4], a[5], u1.z, w1);
      MIX2(a[6], a[7], u1.w, w1);
      MIX2(a[0], a[1], u2.x, w2);
      MIX2(a[2], a[3], u2.y, w2);
      MIX2(a[4], a[5], u2.z, w2);
      MIX2(a[6], a[7], u2.w, w2);
    }
    const float bdv = bdrow[g];
    const float wsv = wsrow[g];
#pragma unroll
    for (int q = 0; q < 8; ++q) p[q] = fmaf(leaky(a[q] + bdv), wsv, p[q]);
  }

  // epilogue: transpose 64b x 128n tile through LDS -> fully coalesced stores.
  // (old path: 32B clusters scattered 4KB apart -> 2.6x write amplification)
  const float bsv = bs[i];
  __syncthreads();                  // done with f16 x-tile
  float* ob = (float*)xs;           // [64][132] f32, col XOR-swizzled by (b>>3)
  const int nl = wv * 8 + n;        // 0..127
#pragma unroll
  for (int q = 0; q < 8; ++q) {
    const int b = j * 8 + q;        // b>>3 == j
    ob[b * 132 + (nl ^ (j << 3))] = leaky(p[q] + bsv);
  }
  __syncthreads();
  const int i0 = blockIdx.x * 128;
  const int bb0 = blockIdx.y * BT;
#pragma unroll
  for (int r = 0; r < 2; ++r) {
    const int t = threadIdx.x + (r << 10);
    const int b = t >> 5;           // 0..63
    const int c4 = (t & 31) << 2;   // 0..124, step 4
    const float4 v = *(const float4*)&ob[b * 132 + (c4 ^ ((b >> 3) << 3))];
    *(float4*)&out[(size_t)(bb0 + b) * N_NEURONS + i0 + c4] = v;
  }
}

extern "C" void kernel_launch(void* const* d_in, const int* in_sizes, int n_in,
                              void* d_out, int out_size, void* d_ws, size_t ws_size,
                              hipStream_t stream) {
  const float* x = (const float*)d_in[0];
  const float* Wd = (const float*)d_in[1];
  const float* bd = (const float*)d_in[2];
  const float* Ws = (const float*)d_in[3];
  const float* bs = (const float*)d_in[4];
  const float* dmask = (const float*)d_in[5];
  float* out = (float*)d_out;

  uint2* pairs = (uint2*)d_ws;                          // 4 MB
  _Float16* xt = (_Float16*)((char*)d_ws + (4 << 20));  // 8 MB

  prep_kernel<<<dim3(4352), dim3(256), 0, stream>>>(x, xt, Wd, dmask, pairs);
  dendrite_kernel<<<dim3(N_NEURONS / 128, NB / BT), dim3(1024), 0, stream>>>(
      xt, pairs, bd, Ws, bs, out);
}

// Round 2
// 341.215 us; speedup vs baseline: 1.1357x; 1.0006x over previous
//
#include <hip/hip_runtime.h>

#define IN_DIM 1024
#define N_NEURONS 1024
#define N_SOMA 16384
#define BT 64          // batch tile
#define NB 4096        // batch size

typedef _Float16 h8 __attribute__((ext_vector_type(8)));

__device__ __forceinline__ float leaky(float v) { return v >= 0.0f ? v : 0.1f * v; }

// acc += (selected f16 half of u) * w, full f32 fma — no separate v_cvt.
#define MIX2(alo, ahi, u, w)                                          \
  asm("v_fma_mix_f32 %0, %2, %3, %0 op_sel_hi:[1,0,0]\n\t"            \
      "v_fma_mix_f32 %1, %2, %3, %1 op_sel:[1,0,0] op_sel_hi:[1,0,0]" \
      : "+v"(alo), "+v"(ahi)                                          \
      : "v"(u), "v"(w))

// one uint4 = two (weight, offset) pairs
#define PAIR_FMA(P4)                                       \
  {                                                        \
    const uint4 u1 = *(const uint4*)(xsb + ((P4).y ^ jx)); \
    const uint4 u2 = *(const uint4*)(xsb + ((P4).w ^ jx)); \
    const float w1 = __uint_as_float((P4).x);              \
    const float w2 = __uint_as_float((P4).z);              \
    MIX2(a[0], a[1], u1.x, w1);                            \
    MIX2(a[2], a[3], u1.y, w1);                            \
    MIX2(a[4], a[5], u1.z, w1);                            \
    MIX2(a[6], a[7], u1.w, w1);                            \
    MIX2(a[0], a[1], u2.x, w2);                            \
    MIX2(a[2], a[3], u2.y, w2);                            \
    MIX2(a[4], a[5], u2.z, w2);                            \
    MIX2(a[6], a[7], u2.w, w2);                            \
  }

// ---- K0 fused prep: blocks [0,4096) compact pairs, [4096,4352) transpose x ----
__global__ __launch_bounds__(256) void prep_kernel(
    const float* __restrict__ x, _Float16* __restrict__ xt,
    const float* __restrict__ Wd, const float* __restrict__ mask,
    uint2* __restrict__ pairs) {
  if (blockIdx.x < 4096) {
    // compact: one wave per soma row. Offset stored with XOR-swizzle baked in:
    // off = (f<<7) | ((f&7)<<4)  -> reader XORs with (j<<4).
    const int lane = threadIdx.x & 63;
    const int s = (blockIdx.x << 2) + (threadIdx.x >> 6);
    const float* mrow = mask + (size_t)s * IN_DIM + lane * 16;
    const float* wrow = Wd + (size_t)s * IN_DIM + lane * 16;
    float m[16], w[16];
#pragma unroll
    for (int k = 0; k < 4; ++k) {
      *(float4*)(m + 4 * k) = *(const float4*)(mrow + 4 * k);
      *(float4*)(w + 4 * k) = *(const float4*)(wrow + 4 * k);
    }
    int c = 0;
#pragma unroll
    for (int k = 0; k < 16; ++k) c += (m[k] != 0.0f) ? 1 : 0;
    int inc = c;
#pragma unroll
    for (int d = 1; d < 64; d <<= 1) {
      int t = __shfl_up(inc, d);
      if (lane >= d) inc += t;
    }
    int pos = inc - c;
    uint2* prow = pairs + ((size_t)s << 5);
#pragma unroll
    for (int k = 0; k < 16; ++k) {
      if (m[k] != 0.0f) {
        if (pos < 32) {
          const unsigned f = (unsigned)(lane * 16 + k);
          prow[pos] = make_uint2(__float_as_uint(w[k] * m[k]),
                                 (f << 7) | ((f & 7) << 4));
        }
        ++pos;
      }
    }
  } else {
    // transpose x [B][F] f32 -> xt tiled [bt][f][64] f16 (coalesced reads)
    const int id = blockIdx.x - 4096;  // 0..255
    const int f = (id & 3) * 256 + threadIdx.x;
    const int bt = id >> 2;
    const int b0 = bt * BT;
    h8* dst = (h8*)xt + ((size_t)bt * IN_DIM + f) * 8;
#pragma unroll
    for (int o = 0; o < 8; ++o) {
      h8 v;
#pragma unroll
      for (int e = 0; e < 8; ++e)
        v[e] = (_Float16)x[(size_t)(b0 + o * 8 + e) * IN_DIM + f];
      dst[o] = v;
    }
  }
}

// ---- K1: fused sparse-dendrite + block-diagonal soma layer ----
// grid (8, 64): x = neuron tile (128), y = batch tile (64). block 1024 = 16 waves.
// wave = 8 neurons (n=lane>>3) x 8 batch-octs (j=lane&7); lane owns 1 neuron x 8 batches.
// launch_bounds(1024,4): 4 waves/SIMD is all LDS (128KB -> 1 block/CU) allows;
// cap VGPR at 128 so the pair stream can be double-buffered in registers.
__global__ __launch_bounds__(1024, 4) void dendrite_kernel(
    const _Float16* __restrict__ xt, const uint2* __restrict__ pairs,
    const float* __restrict__ bd, const float* __restrict__ Ws,
    const float* __restrict__ bs, float* __restrict__ out) {
  __shared__ _Float16 xs[IN_DIM * BT];  // 128 KB; row f = 128 B
  // stage with XOR swizzle: 16B chunk (f,j) -> slot (f, j^(f&7)).
  const uint4* src = (const uint4*)(xt + (size_t)blockIdx.y * IN_DIM * BT);
  uint4* dst = (uint4*)xs;
  for (int q = threadIdx.x; q < IN_DIM * BT * 2 / 16; q += 1024)
    dst[q ^ ((q >> 3) & 7)] = src[q];
  __syncthreads();

  const int lane = threadIdx.x & 63;
  const int wv = threadIdx.x >> 6;  // 0..15
  const int n = lane >> 3;          // neuron within wave
  const int j = lane & 7;           // batch oct
  const unsigned jx = (unsigned)j << 4;
  const int i = blockIdx.x * 128 + wv * 8 + n;  // neuron id
  const char* xsb = (const char*)xs;

  float p[8] = {0.f, 0.f, 0.f, 0.f, 0.f, 0.f, 0.f, 0.f};
  const float* wsrow = Ws + (size_t)i * N_SOMA + (i << 4);
  const float* bdrow = bd + (i << 4);

  // all 16 dendrites of neuron i are 256 contiguous uint4s in pairs[]
  const uint4* prbase = (const uint4*)pairs + ((size_t)i << 8);
  uint4 bufA[8], bufB[8];
#pragma unroll
  for (int t = 0; t < 8; ++t) bufA[t] = prbase[t];  // prime half 0 of g=0

  for (int g = 0; g < 16; ++g) {
    float a[8] = {0.f, 0.f, 0.f, 0.f, 0.f, 0.f, 0.f, 0.f};
    // prefetch half 1 of this g while computing half 0
#pragma unroll
    for (int t = 0; t < 8; ++t) bufB[t] = prbase[g * 16 + 8 + t];
#pragma unroll
    for (int k = 0; k < 8; ++k) PAIR_FMA(bufA[k]);
    // prefetch half 0 of next g while computing half 1 (wraps harmlessly at g=15)
#pragma unroll
    for (int t = 0; t < 8; ++t) bufA[t] = prbase[((g + 1) & 15) * 16 + t];
#pragma unroll
    for (int k = 0; k < 8; ++k) PAIR_FMA(bufB[k]);

    const float bdv = bdrow[g];
    const float wsv = wsrow[g];
#pragma unroll
    for (int q = 0; q < 8; ++q) p[q] = fmaf(leaky(a[q] + bdv), wsv, p[q]);
  }

  // epilogue: transpose 64b x 128n tile through LDS -> fully coalesced stores.
  const float bsv = bs[i];
  __syncthreads();                  // done with f16 x-tile
  float* ob = (float*)xs;           // [64][132] f32, col XOR-swizzled by (b>>3)
  const int nl = wv * 8 + n;        // 0..127
#pragma unroll
  for (int q = 0; q < 8; ++q) {
    const int b = j * 8 + q;        // b>>3 == j
    ob[b * 132 + (nl ^ (j << 3))] = leaky(p[q] + bsv);
  }
  __syncthreads();
  const int i0 = blockIdx.x * 128;
  const int bb0 = blockIdx.y * BT;
#pragma unroll
  for (int r = 0; r < 2; ++r) {
    const int t = threadIdx.x + (r << 10);
    const int b = t >> 5;           // 0..63
    const int c4 = (t & 31) << 2;   // 0..124, step 4
    const float4 v = *(const float4*)&ob[b * 132 + (c4 ^ ((b >> 3) << 3))];
    *(float4*)&out[(size_t)(bb0 + b) * N_NEURONS + i0 + c4] = v;
  }
}

extern "C" void kernel_launch(void* const* d_in, const int* in_sizes, int n_in,
                              void* d_out, int out_size, void* d_ws, size_t ws_size,
                              hipStream_t stream) {
  const float* x = (const float*)d_in[0];
  const float* Wd = (const float*)d_in[1];
  const float* bd = (const float*)d_in[2];
  const float* Ws = (const float*)d_in[3];
  const float* bs = (const float*)d_in[4];
  const float* dmask = (const float*)d_in[5];
  float* out = (float*)d_out;

  uint2* pairs = (uint2*)d_ws;                          // 4 MB
  _Float16* xt = (_Float16*)((char*)d_ws + (4 << 20));  // 8 MB

  prep_kernel<<<dim3(4352), dim3(256), 0, stream>>>(x, xt, Wd, dmask, pairs);
  dendrite_kernel<<<dim3(N_NEURONS / 128, NB / BT), dim3(1024), 0, stream>>>(
      xt, pairs, bd, Ws, bs, out);
}